// Round 2
// baseline (1076.332 us; speedup 1.0000x reference)
//
#include <hip/hip_runtime.h>

// QueryPinnedHopfieldLayer on MI355X (gfx950). fp32 in/out; internal K/V bf16.
// d_out (134.2 MB) doubles as scratch: ln_mb bf16 (76.8 MB, aliased by z/glist/
// phist after gemm), K (25.6), V (25.6), wkv bf16 (0.79), bmax (0.1).
//
// Round-6 changes vs round-5 (961.8 us verified; entmax_k = 3x168.9 us = 53%
// of total, Occupancy 5.2%, VALUBusy 5.4% -- latency-bound on 32/256 CUs):
//  - entmax_k replaced by histogram bracketing, all full-GPU passes:
//      hist_k   (16,32): tau* in [zmax-1, zmax] provably; 512-bin histogram of
//                        (cnt, sum, sumsq) over u=z-lo, atomic-free partials.
//      etau_k   (32):    merge partials; S2(tau_b)=Q-2tS+t^2C exact at bin
//                        boundaries, monotone; suffix-scan -> bracket tau_lo
//                        within 1/512 of tau*.
//      collect_k(16,32): compact candidates {z > tau_lo} -> glist (wave-agg).
//      esolve_k (32):    exact Newton over small LDS list; zeroes xi_out.
//    Predicted: 168.9 us -> ~30 us per step.

typedef unsigned short u16;
typedef unsigned int u32;

typedef __bf16 bf16x8 __attribute__((ext_vector_type(8)));
typedef float f32x4 __attribute__((ext_vector_type(4)));

#define GN 50000
#define NH 4
#define HD 64
#define NB 8
#define MD 768
#define HID 2048
#define NBLK 782
#define NBINS 512
#define NCH 16
#define CHSZ 3125      // 16*3125 = 50000 exactly
#define ECAP 12288

__device__ __forceinline__ float bf2f(u16 u) {
  union { u32 i; float f; } v; v.i = ((u32)u) << 16; return v.f;
}
__device__ __forceinline__ u16 f2bf(float f) {
  u32 x = __float_as_uint(f);
  u32 r = (x + 0x7FFFu + ((x >> 16) & 1u)) >> 16;
  return (u16)r;
}

// ---- scratch layout inside d_out (bytes; 16B aligned) ----
#define LN_OFF    0ull           // 50000*768 bf16 = 76.8 MB (dead after gemm)
#define Z_OFF     0ull           // 32*50000 f32 = 6.4 MB (aliases LN)
#define GLIST_OFF 6400000ull     // 32*50000 f32 = 6.4 MB -> ends 12.8 MB
#define PHIST_OFF 12800000ull    // 16*32*512*3 f32 = 3.15 MB -> ends 15.95 MB
#define K_OFF     76800000ull    // 4*50000*64 bf16
#define V_OFF     102400000ull
#define WKV_OFF   128000000ull   // 512*768 bf16
#define BMAX_OFF  128786432ull   // 32*782 f32 -> ends 128.9 MB < 134.2 MB
// ---- small state in d_ws (proven >= 82944 B) ----
#define XIA_OFF   0u
#define XIB_OFF   8192u
#define T_OFF     16384u
#define BETA_OFF  16512u
#define OUTS_OFF  16640u         // 8*2048 f32 -> ends 82176
#define TLO_OFF   82176u         // 32 f32 -> 82304
#define GCNT_OFF  82304u         // 32 i32 -> ends 82432 (< 82944)

// ---------------- kernels ----------------

// LN(memory_bank) -> bf16, one wave per row (row held in registers)
__global__ __launch_bounds__(256) void row_ln(const float* __restrict__ mb,
                                              const float* __restrict__ gm,
                                              const float* __restrict__ bm,
                                              u16* __restrict__ ln) {
  int row = blockIdx.x * 4 + (threadIdx.x >> 6);
  int lane = threadIdx.x & 63;
  const float4* p4 = (const float4*)(mb + (size_t)row * MD);
  float4 v[3];
  float s = 0.f, ss = 0.f;
#pragma unroll
  for (int j = 0; j < 3; ++j) {
    v[j] = p4[lane + 64 * j];
    s += v[j].x + v[j].y + v[j].z + v[j].w;
    ss += v[j].x * v[j].x + v[j].y * v[j].y + v[j].z * v[j].z + v[j].w * v[j].w;
  }
  for (int o = 32; o > 0; o >>= 1) { s += __shfl_down(s, o); ss += __shfl_down(ss, o); }
  s = __shfl(s, 0); ss = __shfl(ss, 0);
  float m = s * (1.f / 768.f);
  float var = ss * (1.f / 768.f) - m * m;
  float r = rsqrtf(fmaxf(var, 0.f) + 1e-5f);
#pragma unroll
  for (int j = 0; j < 3; ++j) {
    float4 g = ((const float4*)gm)[lane + 64 * j];
    float4 b = ((const float4*)bm)[lane + 64 * j];
    ushort4 o4;
    o4.x = f2bf((v[j].x - m) * r * g.x + b.x);
    o4.y = f2bf((v[j].y - m) * r * g.y + b.y);
    o4.z = f2bf((v[j].z - m) * r * g.z + b.z);
    o4.w = f2bf((v[j].w - m) * r * g.w + b.w);
    *(ushort4*)(ln + (size_t)row * MD + (lane + 64 * j) * 4) = o4;
  }
}

// Wk|Wv fp32 -> bf16 (512x768 flat)
__global__ __launch_bounds__(256) void wconv(const float* __restrict__ Wk,
                                             const float* __restrict__ Wv,
                                             u16* __restrict__ wkv) {
  int i = blockIdx.x * 256 + threadIdx.x;   // float4 index, 98304 total
  float4 v = (i < 49152) ? ((const float4*)Wk)[i] : ((const float4*)Wv)[i - 49152];
  ushort4 o;
  o.x = f2bf(v.x); o.y = f2bf(v.y); o.z = f2bf(v.z); o.w = f2bf(v.w);
  ((ushort4*)wkv)[i] = o;
}

__global__ __launch_bounds__(256) void qprep(const float* __restrict__ qe, const float* __restrict__ Wq,
                                             const float* __restrict__ gq, const float* __restrict__ bq,
                                             const float* __restrict__ lb, float* __restrict__ xi0,
                                             float* __restrict__ beta) {
  int b = blockIdx.x, t = threadIdx.x;
  __shared__ float nq[768];
  __shared__ float w1[4], w2[4];
  float s = 0.f, ss = 0.f;
  for (int j = t; j < 768; j += 256) { float x = qe[b * 768 + j]; s += x; ss += x * x; }
  for (int o = 32; o > 0; o >>= 1) { s += __shfl_down(s, o); ss += __shfl_down(ss, o); }
  if ((t & 63) == 0) { w1[t >> 6] = s; w2[t >> 6] = ss; }
  __syncthreads();
  float S = w1[0] + w1[1] + w1[2] + w1[3];
  float SS = w2[0] + w2[1] + w2[2] + w2[3];
  float m = S * (1.f / 768.f);
  float var = SS * (1.f / 768.f) - m * m;
  float r = rsqrtf(fmaxf(var, 0.f) + 1e-5f);
  for (int j = t; j < 768; j += 256) {
    float x = qe[b * 768 + j];
    nq[j] = (x - m) * r * gq[j] + bq[j];
  }
  __syncthreads();
  const float4* wrow = (const float4*)(Wq + (size_t)t * 768);
  float acc = 0.f;
  for (int k = 0; k < 192; ++k) {
    float4 wv = wrow[k];
    acc += nq[k * 4] * wv.x + nq[k * 4 + 1] * wv.y + nq[k * 4 + 2] * wv.z + nq[k * 4 + 3] * wv.w;
  }
  xi0[b * 256 + t] = acc;
  if (b == 0 && t < 4) beta[t] = expf(lb[t]);
}

// C = ln_mb(bf16) @ wkv^T. BM=64, BN=256, BK=64; 4 waves each 64x64.
__global__ __launch_bounds__(256) void gemm_kv(const u16* __restrict__ ln,
                                               const u16* __restrict__ wkv,
                                               u16* __restrict__ Kbuf, u16* __restrict__ Vbuf) {
  __shared__ u16 As[64][72];
  __shared__ u16 Bs[256][72];
  int t = threadIdx.x;
  int i0 = blockIdx.x * 64;
  int j0 = blockIdx.y;          // 0 -> K, 1 -> V
  int jb = j0 * 256;
  u16* obuf = j0 ? Vbuf : Kbuf;

  int w = t >> 6, lane = t & 63;
  int quad = lane >> 4, l16 = lane & 15;

  f32x4 acc[4][4];
#pragma unroll
  for (int a = 0; a < 4; ++a)
#pragma unroll
    for (int b = 0; b < 4; ++b) { f32x4 zz = {0.f, 0.f, 0.f, 0.f}; acc[a][b] = zz; }

  for (int k0 = 0; k0 < 768; k0 += 64) {
    // stage A: 64x64 bf16, 512 16B chunks
#pragma unroll
    for (int cc = 0; cc < 2; ++cc) {
      int c = t + cc * 256;
      int r = c >> 3, seg = c & 7;
      int row = i0 + r;
      uint4 val = make_uint4(0, 0, 0, 0);
      if (row < GN) val = *(const uint4*)(ln + (size_t)row * MD + k0 + seg * 8);
      *(uint4*)&As[r][seg * 8] = val;
    }
    // stage B: 256x64 bf16, 2048 chunks
#pragma unroll
    for (int cc = 0; cc < 8; ++cc) {
      int c = t + cc * 256;
      int n = c >> 3, seg = c & 7;
      *(uint4*)&Bs[n][seg * 8] = *(const uint4*)(wkv + (size_t)(jb + n) * MD + k0 + seg * 8);
    }
    __syncthreads();
#pragma unroll
    for (int kk = 0; kk < 64; kk += 32) {
      bf16x8 af[4], bfr[4];
#pragma unroll
      for (int tm = 0; tm < 4; ++tm)
        af[tm] = *(const bf16x8*)&As[tm * 16 + l16][kk + quad * 8];
#pragma unroll
      for (int tn = 0; tn < 4; ++tn)
        bfr[tn] = *(const bf16x8*)&Bs[w * 64 + tn * 16 + l16][kk + quad * 8];
#pragma unroll
      for (int tm = 0; tm < 4; ++tm)
#pragma unroll
        for (int tn = 0; tn < 4; ++tn)
          acc[tm][tn] = __builtin_amdgcn_mfma_f32_16x16x32_bf16(af[tm], bfr[tn], acc[tm][tn], 0, 0, 0);
    }
    __syncthreads();
  }
  // epilogue: D row = quad*4+reg (M), col = l16 (N)
#pragma unroll
  for (int tm = 0; tm < 4; ++tm) {
#pragma unroll
    for (int tn = 0; tn < 4; ++tn) {
      int lc = w * 64 + tn * 16 + l16;      // 0..255
      int hh = lc >> 6;
      int dd = lc & 63;
#pragma unroll
      for (int rg = 0; rg < 4; ++rg) {
        int i = i0 + tm * 16 + quad * 4 + rg;
        if (i < GN) obuf[((size_t)hh * GN + i) * HD + dd] = f2bf(acc[tm][tn][rg]);
      }
    }
  }
}

// z[bh][i] = 0.5*beta[h]*xi[b,h,:].K[h,i,:]; per-wave block max -> bmax (no atomics)
__global__ __launch_bounds__(256) void scores_k(const u16* __restrict__ Kbuf, const float* __restrict__ xi,
                                                const float* __restrict__ beta, float* __restrict__ z,
                                                float* __restrict__ bmax) {
  int h = blockIdx.y;
  int row0 = blockIdx.x * 64;
  int t = threadIdx.x;
  __shared__ u16 Ks[64][72];
  __shared__ float xis[8][64];
  {
    int f = t;
    xis[f >> 6][f & 63] = xi[(f >> 6) * 256 + h * 64 + (f & 63)];
    f = t + 256;
    xis[f >> 6][f & 63] = xi[(f >> 6) * 256 + h * 64 + (f & 63)];
  }
  {
    int r = t >> 3, d0 = (t & 7) * 8;
#pragma unroll
    for (int rr = 0; rr < 2; ++rr) {
      int ri = r + rr * 32;
      int row = row0 + ri;
      uint4 val = make_uint4(0, 0, 0, 0);
      if (row < GN) val = *(const uint4*)(Kbuf + ((size_t)h * GN + row) * HD + d0);
      *(uint4*)&Ks[ri][d0] = val;
    }
  }
  __syncthreads();
  int i = t & 63, bg = t >> 6;
  float a0 = 0.f, a1 = 0.f;
#pragma unroll
  for (int dd = 0; dd < 64; dd += 4) {
    ushort4 k4 = *(const ushort4*)&Ks[i][dd];
    float4 x0 = *(const float4*)&xis[bg][dd];
    float4 x1 = *(const float4*)&xis[bg + 4][dd];
    float k0 = bf2f(k4.x), k1 = bf2f(k4.y), k2 = bf2f(k4.z), k3 = bf2f(k4.w);
    a0 += k0 * x0.x + k1 * x0.y + k2 * x0.z + k3 * x0.w;
    a1 += k0 * x1.x + k1 * x1.y + k2 * x1.z + k3 * x1.w;
  }
  float bh = beta[h];
  float z0 = 0.5f * bh * a0;
  float z1 = 0.5f * bh * a1;
  int row = row0 + i;
  if (row < GN) {
    z[((size_t)(bg * 4 + h)) * GN + row] = z0;
    z[((size_t)((bg + 4) * 4 + h)) * GN + row] = z1;
  } else {
    z0 = -1e30f; z1 = -1e30f;
  }
  for (int o = 32; o > 0; o >>= 1) {
    z0 = fmaxf(z0, __shfl_down(z0, o));
    z1 = fmaxf(z1, __shfl_down(z1, o));
  }
  if (i == 0) {
    bmax[(size_t)(bg * 4 + h) * NBLK + blockIdx.x] = z0;
    bmax[(size_t)((bg + 4) * 4 + h) * NBLK + blockIdx.x] = z1;
  }
}

// all-thread block max over bmax[bh][0..NBLK)
__device__ __forceinline__ float gmax_of(const float* __restrict__ bmax, int bh, int t, float* red) {
  float m = -1e30f;
  for (int i = t; i < NBLK; i += 256) m = fmaxf(m, bmax[(size_t)bh * NBLK + i]);
  for (int o = 32; o > 0; o >>= 1) m = fmaxf(m, __shfl_down(m, o));
  if ((t & 63) == 0) red[t >> 6] = m;
  __syncthreads();
  return fmaxf(fmaxf(red[0], red[1]), fmaxf(red[2], red[3]));
}

// 512-bin histogram of u = z - (gmax-1) in (0,1]: per-chunk partials (no global atomics)
__global__ __launch_bounds__(256) void hist_k(const float* __restrict__ z,
                                              const float* __restrict__ bmax,
                                              float* __restrict__ phist) {
  int ch = blockIdx.x;   // 0..15
  int bh = blockIdx.y;   // 0..31
  int t = threadIdx.x;
  __shared__ float hcnt[NBINS], hsum[NBINS], hsq[NBINS];
  __shared__ float red[4];
  for (int b = t; b < NBINS; b += 256) { hcnt[b] = 0.f; hsum[b] = 0.f; hsq[b] = 0.f; }
  float gmx = gmax_of(bmax, bh, t, red);   // includes a __syncthreads
  float lo = gmx - 1.f;
  const float* zp = z + (size_t)bh * GN;
  int base = ch * CHSZ;
  for (int i = base + t; i < base + CHSZ; i += 256) {
    float u = zp[i] - lo;
    if (u > 0.f) {
      int idx = (int)(u * (float)NBINS);
      if (idx > NBINS - 1) idx = NBINS - 1;
      atomicAdd(&hcnt[idx], 1.f);
      atomicAdd(&hsum[idx], u);
      atomicAdd(&hsq[idx], u * u);
    }
  }
  __syncthreads();
  float* out = phist + ((size_t)(ch * 32 + bh)) * NBINS * 3;
  for (int b = t; b < NBINS; b += 256) {
    out[b * 3 + 0] = hcnt[b];
    out[b * 3 + 1] = hsum[b];
    out[b * 3 + 2] = hsq[b];
  }
}

// merge partials; suffix-scan top-down; S2(tau_b) = Q - 2t'S + t'^2 C exact at
// boundaries; largest b with S2>=1 brackets tau*. Writes tlo[bh], gcnt[bh]=0.
__global__ __launch_bounds__(256) void etau_k(const float* __restrict__ phist,
                                              const float* __restrict__ bmax,
                                              float* __restrict__ tlo, int* __restrict__ gcnt) {
  int bh = blockIdx.x;
  int t = threadIdx.x;
  __shared__ float hcnt[NBINS], hsum[NBINS], hsq[NBINS];
  __shared__ float red[4];
  for (int b = t; b < NBINS; b += 256) {
    float c = 0.f, s = 0.f, q = 0.f;
    for (int ch = 0; ch < NCH; ++ch) {
      const float* p = phist + ((size_t)(ch * 32 + bh)) * NBINS * 3 + b * 3;
      c += p[0]; s += p[1]; q += p[2];
    }
    hcnt[b] = c; hsum[b] = s; hsq[b] = q;
  }
  float gmx = gmax_of(bmax, bh, t, red);   // includes a __syncthreads (covers hist write)
  __syncthreads();
  if (t == 0) {
    float lo = gmx - 1.f;
    float C = 0.f, S = 0.f, Q = 0.f;
    int found = 0;
    const float w = 1.f / (float)NBINS;
    for (int b = NBINS - 1; b >= 0; --b) {
      C += hcnt[b]; S += hsum[b]; Q += hsq[b];
      float tp = (float)b * w;
      float s2 = Q - 2.f * tp * S + tp * tp * C;
      if (s2 >= 1.f) { found = b; break; }
    }
    tlo[bh] = lo + (float)found * w;
    gcnt[bh] = 0;
  }
}

// compact candidates {z > tlo[bh]} into glist via wave-aggregated global atomics
__global__ __launch_bounds__(256) void collect_k(const float* __restrict__ z,
                                                 const float* __restrict__ tlo,
                                                 float* __restrict__ glist, int* __restrict__ gcnt) {
  int ch = blockIdx.x;   // 0..15
  int bh = blockIdx.y;   // 0..31
  int t = threadIdx.x, lane = t & 63;
  float tl = tlo[bh];
  const float* zp = z + (size_t)bh * GN;
  float* gl = glist + (size_t)bh * GN;
  int base = ch * CHSZ;
  for (int i = base + t; i < base + CHSZ; i += 256) {
    float zv = zp[i];
    bool keep = zv > tl;
    unsigned long long mk = __ballot(keep);
    if (mk) {
      int leader = __ffsll(mk) - 1;
      int gbase = 0;
      if (lane == leader) gbase = atomicAdd(&gcnt[bh], (int)__popcll(mk));
      gbase = __shfl(gbase, leader);
      if (keep) {
        int pos = gbase + (int)__popcll(mk & ((1ull << lane) - 1ull));
        gl[pos] = zv;
      }
    }
  }
}

// exact Newton over candidate list (LDS if it fits); zeroes xi_out
__global__ __launch_bounds__(512) void esolve_k(const float* __restrict__ glist,
                                                const int* __restrict__ gcnt,
                                                const float* __restrict__ tlo,
                                                float* __restrict__ T, float* __restrict__ xout) {
  int bh = blockIdx.x;
  int t = threadIdx.x, w = t >> 6, lane = t & 63;
  __shared__ float list[ECAP];
  __shared__ float rs1[8], rs2[8];
  __shared__ float tsh, dsh;
  int n = gcnt[bh];
  const float* gl = glist + (size_t)bh * GN;
  bool inlds = (n <= ECAP);
  if (inlds) for (int i = t; i < n; i += 512) list[i] = gl[i];
  float tau = tlo[bh];
  __syncthreads();
  for (int it = 0; it < 24; ++it) {
    float s1 = 0.f, s2 = 0.f;
    if (inlds) {
      for (int i = t; i < n; i += 512) {
        float d = fmaxf(list[i] - tau, 0.f);
        s1 += d; s2 += d * d;
      }
    } else {
      for (int i = t; i < n; i += 512) {
        float d = fmaxf(gl[i] - tau, 0.f);
        s1 += d; s2 += d * d;
      }
    }
    for (int o = 32; o > 0; o >>= 1) { s1 += __shfl_down(s1, o); s2 += __shfl_down(s2, o); }
    if (lane == 0) { rs1[w] = s1; rs2[w] = s2; }
    __syncthreads();
    if (t == 0) {
      float S1 = 0.f, S2 = 0.f;
#pragma unroll
      for (int q = 0; q < 8; ++q) { S1 += rs1[q]; S2 += rs2[q]; }
      float dt = (S2 - 1.f) / (2.f * fmaxf(S1, 1e-12f));
      tsh = tau + dt; dsh = dt;
    }
    __syncthreads();
    tau = tsh;
    if (fabsf(dsh) < 1e-7f) break;
  }
  if (t == 0) T[bh] = tau;
  if (t < 64) xout[bh * 64 + t] = 0.f;
}

// xi_new[b,h,d] += sum_i ((z-T)+)^2 * V[h,i,d]; skip all-zero groups of 8 rows
__global__ __launch_bounds__(512) void xiupd_k(const float* __restrict__ z, const float* __restrict__ T,
                                               const u16* __restrict__ Vbuf, float* __restrict__ xi_new) {
  int h = blockIdx.y;
  int row0 = blockIdx.x * 1024;
  int t = threadIdx.x;
  int b = t >> 6, d = t & 63;
  __shared__ float zs[8][1024];
#pragma unroll
  for (int j = 0; j < 16; ++j) {
    int f = t + j * 512;
    int bb = f >> 10, i = f & 1023;
    int row = row0 + i;
    zs[bb][i] = (row < GN) ? z[((size_t)(bb * 4 + h)) * GN + row] : -1e30f;
  }
  __syncthreads();
  float Tv = T[b * 4 + h];
  float acc = 0.f;
  for (int ii = 0; ii < 1024; ii += 8) {
    float wv[8];
#pragma unroll
    for (int e = 0; e < 8; ++e) wv[e] = zs[b][ii + e] - Tv;
    float m8 = wv[0];
#pragma unroll
    for (int e = 1; e < 8; ++e) m8 = fmaxf(m8, wv[e]);
    if (m8 <= 0.f) continue;
    const u16* vrow = Vbuf + ((size_t)h * GN + row0 + ii) * HD + d;
#pragma unroll
    for (int e = 0; e < 8; ++e) {
      float we = fmaxf(wv[e], 0.f);
      float v = bf2f(vrow[e * HD]);
      acc += we * we * v;
    }
  }
  atomicAdd(&xi_new[b * 256 + h * 64 + d], acc);
}

__global__ __launch_bounds__(256) void finout_k(const float* __restrict__ xi, const float* __restrict__ Wo,
                                                float* __restrict__ outs) {
  int w = threadIdx.x >> 6, lane = threadIdx.x & 63;
  int flat = blockIdx.x * 4 + w;
  int b = flat >> 11, o = flat & 2047;
  const float4* wp = (const float4*)(Wo + (size_t)o * 256);
  const float4* xp = (const float4*)(xi + b * 256);
  float4 w4 = wp[lane];
  float4 x4 = xp[lane];
  float acc = w4.x * x4.x + w4.y * x4.y + w4.z * x4.z + w4.w * x4.w;
  for (int o2 = 32; o2 > 0; o2 >>= 1) acc += __shfl_down(acc, o2);
  if (lane == 0) outs[flat] = acc;
}

__global__ __launch_bounds__(256) void bcast_k(const float* __restrict__ outs, float* __restrict__ out) {
  int idx = blockIdx.x * 256 + threadIdx.x;   // float4 index; rows are 512 float4
  int row = idx >> 9, o = idx & 511;
  int b = row >> 11;
  ((float4*)out)[idx] = ((const float4*)outs)[b * 512 + o];
}

// ---------------- launch ----------------
extern "C" void kernel_launch(void* const* d_in, const int* in_sizes, int n_in,
                              void* d_out, int out_size, void* d_ws, size_t ws_size,
                              hipStream_t stream) {
  const float* qe = (const float*)d_in[1];
  const float* mb = (const float*)d_in[2];
  const float* Wq = (const float*)d_in[3];
  const float* Wk = (const float*)d_in[4];
  const float* Wv = (const float*)d_in[5];
  const float* Wo = (const float*)d_in[6];
  const float* lb = (const float*)d_in[7];
  const float* gq = (const float*)d_in[8];
  const float* bq = (const float*)d_in[9];
  const float* gm = (const float*)d_in[10];
  const float* bm = (const float*)d_in[11];

  char* ob = (char*)d_out;
  u16*   ln    = (u16*)(ob + LN_OFF);
  float* z     = (float*)(ob + Z_OFF);
  float* glist = (float*)(ob + GLIST_OFF);
  float* phist = (float*)(ob + PHIST_OFF);
  u16*   Kb    = (u16*)(ob + K_OFF);
  u16*   Vb    = (u16*)(ob + V_OFF);
  u16*   wkv   = (u16*)(ob + WKV_OFF);
  float* bmax  = (float*)(ob + BMAX_OFF);

  char* ws = (char*)d_ws;
  float* xiA  = (float*)(ws + XIA_OFF);
  float* xiB  = (float*)(ws + XIB_OFF);
  float* T    = (float*)(ws + T_OFF);
  float* beta = (float*)(ws + BETA_OFF);
  float* outs = (float*)(ws + OUTS_OFF);
  float* tlo  = (float*)(ws + TLO_OFF);
  int*   gcnt = (int*)(ws + GCNT_OFF);

  row_ln<<<12500, 256, 0, stream>>>(mb, gm, bm, ln);
  wconv<<<384, 256, 0, stream>>>(Wk, Wv, wkv);
  qprep<<<8, 256, 0, stream>>>(qe, Wq, gq, bq, lb, xiA, beta);
  gemm_kv<<<dim3(782, 2), 256, 0, stream>>>(ln, wkv, Kb, Vb);

  float* xin = xiA;
  float* xout = xiB;
  for (int s = 0; s < 3; ++s) {
    scores_k<<<dim3(782, 4), 256, 0, stream>>>(Kb, xin, beta, z, bmax);
    hist_k<<<dim3(NCH, 32), 256, 0, stream>>>(z, bmax, phist);
    etau_k<<<32, 256, 0, stream>>>(phist, bmax, tlo, gcnt);
    collect_k<<<dim3(NCH, 32), 256, 0, stream>>>(z, tlo, glist, gcnt);
    esolve_k<<<32, 512, 0, stream>>>(glist, gcnt, tlo, T, xout);
    xiupd_k<<<dim3(49, 4), 512, 0, stream>>>(z, T, Vb, xout);
    float* tmp = xin; xin = xout; xout = tmp;
  }

  finout_k<<<4096, 256, 0, stream>>>(xin, Wo, outs);
  bcast_k<<<32768, 256, 0, stream>>>(outs, (float*)d_out);
}

// Round 3
// 752.655 us; speedup vs baseline: 1.4300x; 1.4300x over previous
//
#include <hip/hip_runtime.h>

// QueryPinnedHopfieldLayer on MI355X (gfx950). fp32 in/out; internal K/V bf16.
// d_out (134.2 MB) doubles as scratch: ln_mb bf16 (76.8 MB, aliased by z/glist/
// phist after gemm), K (25.6), V (25.6), wkv bf16 (0.79), bmax (0.1), ccnt.
//
// Round-7 changes vs round-6 (1076 us; collect_k = 3x152 us, VALUBusy 0.6%,
// HBM 0.5% -- pure serialization on returning atomicAdd to 32 gcnt counters
// in 2 cachelines, cross-XCD line bouncing):
//  - collect_k: global atomics ELIMINATED. Each (ch,bh) block compacts its
//    private 3125-elem slice into a fixed per-chunk segment of glist
//    (survivors <= 3125 by construction) using one LDS counter; writes its
//    count to ccnt[bh][ch] with a plain store.
//  - esolve_k: prefix-sums the 16 chunk counts, stages segments into LDS,
//    exact Newton as before (identical numerics -> absmax unchanged).
//  - etau_k: publishes (lo, b1) per bh; keep-test in collect uses the same
//    integer bin criterion as hist_k, so candidates provably cover support.

typedef unsigned short u16;
typedef unsigned int u32;

typedef __bf16 bf16x8 __attribute__((ext_vector_type(8)));
typedef float f32x4 __attribute__((ext_vector_type(4)));

#define GN 50000
#define NH 4
#define HD 64
#define NB 8
#define MD 768
#define HID 2048
#define NBLK 782
#define NBINS 512
#define NCH 16
#define CHSZ 3125      // 16*3125 = 50000 exactly; also the per-chunk segment stride
#define ECAP 12288

__device__ __forceinline__ float bf2f(u16 u) {
  union { u32 i; float f; } v; v.i = ((u32)u) << 16; return v.f;
}
__device__ __forceinline__ u16 f2bf(float f) {
  u32 x = __float_as_uint(f);
  u32 r = (x + 0x7FFFu + ((x >> 16) & 1u)) >> 16;
  return (u16)r;
}

// ---- scratch layout inside d_out (bytes; 16B aligned) ----
#define LN_OFF    0ull           // 50000*768 bf16 = 76.8 MB (dead after gemm)
#define Z_OFF     0ull           // 32*50000 f32 = 6.4 MB (aliases LN)
#define GLIST_OFF 6400000ull     // 32*50000 f32 = 6.4 MB -> ends 12.8 MB
#define PHIST_OFF 12800000ull    // 16*32*512*3 f32 = 3.15 MB -> ends 15.95 MB
#define K_OFF     76800000ull    // 4*50000*64 bf16
#define V_OFF     102400000ull
#define WKV_OFF   128000000ull   // 512*768 bf16
#define BMAX_OFF  128786432ull   // 32*782 f32 -> ends 128.9 MB
#define CCNT_OFF  130000000ull   // 32*16 i32 = 2 KB -> ends 130.002 MB < 134.2 MB
// ---- small state in d_ws (proven >= 82944 B) ----
#define XIA_OFF   0u
#define XIB_OFF   8192u
#define T_OFF     16384u
#define BETA_OFF  16512u
#define OUTS_OFF  16640u         // 8*2048 f32 -> ends 82176
#define EP_OFF    82176u         // 32*2 f32 (lo, b1) -> ends 82432 (< 82944)

// ---------------- kernels ----------------

// LN(memory_bank) -> bf16, one wave per row (row held in registers)
__global__ __launch_bounds__(256) void row_ln(const float* __restrict__ mb,
                                              const float* __restrict__ gm,
                                              const float* __restrict__ bm,
                                              u16* __restrict__ ln) {
  int row = blockIdx.x * 4 + (threadIdx.x >> 6);
  int lane = threadIdx.x & 63;
  const float4* p4 = (const float4*)(mb + (size_t)row * MD);
  float4 v[3];
  float s = 0.f, ss = 0.f;
#pragma unroll
  for (int j = 0; j < 3; ++j) {
    v[j] = p4[lane + 64 * j];
    s += v[j].x + v[j].y + v[j].z + v[j].w;
    ss += v[j].x * v[j].x + v[j].y * v[j].y + v[j].z * v[j].z + v[j].w * v[j].w;
  }
  for (int o = 32; o > 0; o >>= 1) { s += __shfl_down(s, o); ss += __shfl_down(ss, o); }
  s = __shfl(s, 0); ss = __shfl(ss, 0);
  float m = s * (1.f / 768.f);
  float var = ss * (1.f / 768.f) - m * m;
  float r = rsqrtf(fmaxf(var, 0.f) + 1e-5f);
#pragma unroll
  for (int j = 0; j < 3; ++j) {
    float4 g = ((const float4*)gm)[lane + 64 * j];
    float4 b = ((const float4*)bm)[lane + 64 * j];
    ushort4 o4;
    o4.x = f2bf((v[j].x - m) * r * g.x + b.x);
    o4.y = f2bf((v[j].y - m) * r * g.y + b.y);
    o4.z = f2bf((v[j].z - m) * r * g.z + b.z);
    o4.w = f2bf((v[j].w - m) * r * g.w + b.w);
    *(ushort4*)(ln + (size_t)row * MD + (lane + 64 * j) * 4) = o4;
  }
}

// Wk|Wv fp32 -> bf16 (512x768 flat)
__global__ __launch_bounds__(256) void wconv(const float* __restrict__ Wk,
                                             const float* __restrict__ Wv,
                                             u16* __restrict__ wkv) {
  int i = blockIdx.x * 256 + threadIdx.x;   // float4 index, 98304 total
  float4 v = (i < 49152) ? ((const float4*)Wk)[i] : ((const float4*)Wv)[i - 49152];
  ushort4 o;
  o.x = f2bf(v.x); o.y = f2bf(v.y); o.z = f2bf(v.z); o.w = f2bf(v.w);
  ((ushort4*)wkv)[i] = o;
}

__global__ __launch_bounds__(256) void qprep(const float* __restrict__ qe, const float* __restrict__ Wq,
                                             const float* __restrict__ gq, const float* __restrict__ bq,
                                             const float* __restrict__ lb, float* __restrict__ xi0,
                                             float* __restrict__ beta) {
  int b = blockIdx.x, t = threadIdx.x;
  __shared__ float nq[768];
  __shared__ float w1[4], w2[4];
  float s = 0.f, ss = 0.f;
  for (int j = t; j < 768; j += 256) { float x = qe[b * 768 + j]; s += x; ss += x * x; }
  for (int o = 32; o > 0; o >>= 1) { s += __shfl_down(s, o); ss += __shfl_down(ss, o); }
  if ((t & 63) == 0) { w1[t >> 6] = s; w2[t >> 6] = ss; }
  __syncthreads();
  float S = w1[0] + w1[1] + w1[2] + w1[3];
  float SS = w2[0] + w2[1] + w2[2] + w2[3];
  float m = S * (1.f / 768.f);
  float var = SS * (1.f / 768.f) - m * m;
  float r = rsqrtf(fmaxf(var, 0.f) + 1e-5f);
  for (int j = t; j < 768; j += 256) {
    float x = qe[b * 768 + j];
    nq[j] = (x - m) * r * gq[j] + bq[j];
  }
  __syncthreads();
  const float4* wrow = (const float4*)(Wq + (size_t)t * 768);
  float acc = 0.f;
  for (int k = 0; k < 192; ++k) {
    float4 wv = wrow[k];
    acc += nq[k * 4] * wv.x + nq[k * 4 + 1] * wv.y + nq[k * 4 + 2] * wv.z + nq[k * 4 + 3] * wv.w;
  }
  xi0[b * 256 + t] = acc;
  if (b == 0 && t < 4) beta[t] = expf(lb[t]);
}

// C = ln_mb(bf16) @ wkv^T. BM=64, BN=256, BK=64; 4 waves each 64x64.
__global__ __launch_bounds__(256) void gemm_kv(const u16* __restrict__ ln,
                                               const u16* __restrict__ wkv,
                                               u16* __restrict__ Kbuf, u16* __restrict__ Vbuf) {
  __shared__ u16 As[64][72];
  __shared__ u16 Bs[256][72];
  int t = threadIdx.x;
  int i0 = blockIdx.x * 64;
  int j0 = blockIdx.y;          // 0 -> K, 1 -> V
  int jb = j0 * 256;
  u16* obuf = j0 ? Vbuf : Kbuf;

  int w = t >> 6, lane = t & 63;
  int quad = lane >> 4, l16 = lane & 15;

  f32x4 acc[4][4];
#pragma unroll
  for (int a = 0; a < 4; ++a)
#pragma unroll
    for (int b = 0; b < 4; ++b) { f32x4 zz = {0.f, 0.f, 0.f, 0.f}; acc[a][b] = zz; }

  for (int k0 = 0; k0 < 768; k0 += 64) {
    // stage A: 64x64 bf16, 512 16B chunks
#pragma unroll
    for (int cc = 0; cc < 2; ++cc) {
      int c = t + cc * 256;
      int r = c >> 3, seg = c & 7;
      int row = i0 + r;
      uint4 val = make_uint4(0, 0, 0, 0);
      if (row < GN) val = *(const uint4*)(ln + (size_t)row * MD + k0 + seg * 8);
      *(uint4*)&As[r][seg * 8] = val;
    }
    // stage B: 256x64 bf16, 2048 chunks
#pragma unroll
    for (int cc = 0; cc < 8; ++cc) {
      int c = t + cc * 256;
      int n = c >> 3, seg = c & 7;
      *(uint4*)&Bs[n][seg * 8] = *(const uint4*)(wkv + (size_t)(jb + n) * MD + k0 + seg * 8);
    }
    __syncthreads();
#pragma unroll
    for (int kk = 0; kk < 64; kk += 32) {
      bf16x8 af[4], bfr[4];
#pragma unroll
      for (int tm = 0; tm < 4; ++tm)
        af[tm] = *(const bf16x8*)&As[tm * 16 + l16][kk + quad * 8];
#pragma unroll
      for (int tn = 0; tn < 4; ++tn)
        bfr[tn] = *(const bf16x8*)&Bs[w * 64 + tn * 16 + l16][kk + quad * 8];
#pragma unroll
      for (int tm = 0; tm < 4; ++tm)
#pragma unroll
        for (int tn = 0; tn < 4; ++tn)
          acc[tm][tn] = __builtin_amdgcn_mfma_f32_16x16x32_bf16(af[tm], bfr[tn], acc[tm][tn], 0, 0, 0);
    }
    __syncthreads();
  }
  // epilogue: D row = quad*4+reg (M), col = l16 (N)
#pragma unroll
  for (int tm = 0; tm < 4; ++tm) {
#pragma unroll
    for (int tn = 0; tn < 4; ++tn) {
      int lc = w * 64 + tn * 16 + l16;      // 0..255
      int hh = lc >> 6;
      int dd = lc & 63;
#pragma unroll
      for (int rg = 0; rg < 4; ++rg) {
        int i = i0 + tm * 16 + quad * 4 + rg;
        if (i < GN) obuf[((size_t)hh * GN + i) * HD + dd] = f2bf(acc[tm][tn][rg]);
      }
    }
  }
}

// z[bh][i] = 0.5*beta[h]*xi[b,h,:].K[h,i,:]; per-wave block max -> bmax (no atomics)
__global__ __launch_bounds__(256) void scores_k(const u16* __restrict__ Kbuf, const float* __restrict__ xi,
                                                const float* __restrict__ beta, float* __restrict__ z,
                                                float* __restrict__ bmax) {
  int h = blockIdx.y;
  int row0 = blockIdx.x * 64;
  int t = threadIdx.x;
  __shared__ u16 Ks[64][72];
  __shared__ float xis[8][64];
  {
    int f = t;
    xis[f >> 6][f & 63] = xi[(f >> 6) * 256 + h * 64 + (f & 63)];
    f = t + 256;
    xis[f >> 6][f & 63] = xi[(f >> 6) * 256 + h * 64 + (f & 63)];
  }
  {
    int r = t >> 3, d0 = (t & 7) * 8;
#pragma unroll
    for (int rr = 0; rr < 2; ++rr) {
      int ri = r + rr * 32;
      int row = row0 + ri;
      uint4 val = make_uint4(0, 0, 0, 0);
      if (row < GN) val = *(const uint4*)(Kbuf + ((size_t)h * GN + row) * HD + d0);
      *(uint4*)&Ks[ri][d0] = val;
    }
  }
  __syncthreads();
  int i = t & 63, bg = t >> 6;
  float a0 = 0.f, a1 = 0.f;
#pragma unroll
  for (int dd = 0; dd < 64; dd += 4) {
    ushort4 k4 = *(const ushort4*)&Ks[i][dd];
    float4 x0 = *(const float4*)&xis[bg][dd];
    float4 x1 = *(const float4*)&xis[bg + 4][dd];
    float k0 = bf2f(k4.x), k1 = bf2f(k4.y), k2 = bf2f(k4.z), k3 = bf2f(k4.w);
    a0 += k0 * x0.x + k1 * x0.y + k2 * x0.z + k3 * x0.w;
    a1 += k0 * x1.x + k1 * x1.y + k2 * x1.z + k3 * x1.w;
  }
  float bh = beta[h];
  float z0 = 0.5f * bh * a0;
  float z1 = 0.5f * bh * a1;
  int row = row0 + i;
  if (row < GN) {
    z[((size_t)(bg * 4 + h)) * GN + row] = z0;
    z[((size_t)((bg + 4) * 4 + h)) * GN + row] = z1;
  } else {
    z0 = -1e30f; z1 = -1e30f;
  }
  for (int o = 32; o > 0; o >>= 1) {
    z0 = fmaxf(z0, __shfl_down(z0, o));
    z1 = fmaxf(z1, __shfl_down(z1, o));
  }
  if (i == 0) {
    bmax[(size_t)(bg * 4 + h) * NBLK + blockIdx.x] = z0;
    bmax[(size_t)((bg + 4) * 4 + h) * NBLK + blockIdx.x] = z1;
  }
}

// all-thread block max over bmax[bh][0..NBLK)
__device__ __forceinline__ float gmax_of(const float* __restrict__ bmax, int bh, int t, float* red) {
  float m = -1e30f;
  for (int i = t; i < NBLK; i += 256) m = fmaxf(m, bmax[(size_t)bh * NBLK + i]);
  for (int o = 32; o > 0; o >>= 1) m = fmaxf(m, __shfl_down(m, o));
  if ((t & 63) == 0) red[t >> 6] = m;
  __syncthreads();
  return fmaxf(fmaxf(red[0], red[1]), fmaxf(red[2], red[3]));
}

// 512-bin histogram of u = z - (gmax-1) in (0,1]: per-chunk partials (no global atomics)
__global__ __launch_bounds__(256) void hist_k(const float* __restrict__ z,
                                              const float* __restrict__ bmax,
                                              float* __restrict__ phist) {
  int ch = blockIdx.x;   // 0..15
  int bh = blockIdx.y;   // 0..31
  int t = threadIdx.x;
  __shared__ float hcnt[NBINS], hsum[NBINS], hsq[NBINS];
  __shared__ float red[4];
  for (int b = t; b < NBINS; b += 256) { hcnt[b] = 0.f; hsum[b] = 0.f; hsq[b] = 0.f; }
  float gmx = gmax_of(bmax, bh, t, red);   // includes a __syncthreads
  float lo = gmx - 1.f;
  const float* zp = z + (size_t)bh * GN;
  int base = ch * CHSZ;
  for (int i = base + t; i < base + CHSZ; i += 256) {
    float u = zp[i] - lo;
    if (u > 0.f) {
      int idx = (int)(u * (float)NBINS);
      if (idx > NBINS - 1) idx = NBINS - 1;
      atomicAdd(&hcnt[idx], 1.f);
      atomicAdd(&hsum[idx], u);
      atomicAdd(&hsq[idx], u * u);
    }
  }
  __syncthreads();
  float* out = phist + ((size_t)(ch * 32 + bh)) * NBINS * 3;
  for (int b = t; b < NBINS; b += 256) {
    out[b * 3 + 0] = hcnt[b];
    out[b * 3 + 1] = hsum[b];
    out[b * 3 + 2] = hsq[b];
  }
}

// merge partials; suffix-scan top-down; S2(tau_b) = Q - 2t'S + t'^2 C exact at
// boundaries; largest b with S2>=1 brackets tau*. Writes ep[bh] = (lo, b1).
__global__ __launch_bounds__(256) void etau_k(const float* __restrict__ phist,
                                              const float* __restrict__ bmax,
                                              float* __restrict__ ep) {
  int bh = blockIdx.x;
  int t = threadIdx.x;
  __shared__ float hcnt[NBINS], hsum[NBINS], hsq[NBINS];
  __shared__ float red[4];
  for (int b = t; b < NBINS; b += 256) {
    float c = 0.f, s = 0.f, q = 0.f;
    for (int ch = 0; ch < NCH; ++ch) {
      const float* p = phist + ((size_t)(ch * 32 + bh)) * NBINS * 3 + b * 3;
      c += p[0]; s += p[1]; q += p[2];
    }
    hcnt[b] = c; hsum[b] = s; hsq[b] = q;
  }
  float gmx = gmax_of(bmax, bh, t, red);   // includes a __syncthreads (covers hist write)
  __syncthreads();
  if (t == 0) {
    float lo = gmx - 1.f;
    float C = 0.f, S = 0.f, Q = 0.f;
    int found = 0;
    const float w = 1.f / (float)NBINS;
    for (int b = NBINS - 1; b >= 0; --b) {
      C += hcnt[b]; S += hsum[b]; Q += hsq[b];
      float tp = (float)b * w;
      float s2 = Q - 2.f * tp * S + tp * tp * C;
      if (s2 >= 1.f) { found = b; break; }
    }
    ep[bh * 2 + 0] = lo;
    ep[bh * 2 + 1] = (float)found;
  }
}

// compact candidates {bin >= b1} into PRIVATE per-chunk segments; LDS counter
// only (no global atomics); plain-store the count.
__global__ __launch_bounds__(256) void collect_k(const float* __restrict__ z,
                                                 const float* __restrict__ ep,
                                                 float* __restrict__ glist, int* __restrict__ ccnt) {
  int ch = blockIdx.x;   // 0..15
  int bh = blockIdx.y;   // 0..31
  int t = threadIdx.x;
  __shared__ int cnt;
  if (t == 0) cnt = 0;
  __syncthreads();
  float lo = ep[bh * 2 + 0];
  int b1 = (int)ep[bh * 2 + 1];
  const float* zp = z + (size_t)bh * GN;
  float* seg = glist + (size_t)bh * GN + ch * CHSZ;   // private segment, cap 3125
  int base = ch * CHSZ;
  for (int i = base + t; i < base + CHSZ; i += 256) {
    float zv = zp[i];
    float u = zv - lo;
    if (u > 0.f) {
      int idx = (int)(u * (float)NBINS);
      if (idx > NBINS - 1) idx = NBINS - 1;
      if (idx >= b1) {
        int p = atomicAdd(&cnt, 1);   // LDS atomic: cheap, block-local
        seg[p] = zv;
      }
    }
  }
  __syncthreads();
  if (t == 0) ccnt[bh * NCH + ch] = cnt;
}

// exact Newton over candidate list (segments staged to LDS); zeroes xi_out
__global__ __launch_bounds__(512) void esolve_k(const float* __restrict__ glist,
                                                const int* __restrict__ ccnt,
                                                const float* __restrict__ ep,
                                                float* __restrict__ T, float* __restrict__ xout) {
  int bh = blockIdx.x;
  int t = threadIdx.x, w = t >> 6, lane = t & 63;
  __shared__ float list[ECAP];
  __shared__ float rs1[8], rs2[8];
  __shared__ float tsh, dsh;
  __shared__ int cbase[NCH + 1];
  if (t == 0) {
    int a = 0;
    for (int c = 0; c < NCH; ++c) { cbase[c] = a; a += ccnt[bh * NCH + c]; }
    cbase[NCH] = a;
  }
  __syncthreads();
  int ntot = cbase[NCH];
  const float* gl = glist + (size_t)bh * GN;
  bool inlds = (ntot <= ECAP);
  if (inlds) {
    for (int c = 0; c < NCH; ++c) {
      int n = cbase[c + 1] - cbase[c];
      for (int i = t; i < n; i += 512) list[cbase[c] + i] = gl[c * CHSZ + i];
    }
  }
  float tau = ep[bh * 2 + 0] + ((float)(int)ep[bh * 2 + 1]) * (1.f / (float)NBINS);
  __syncthreads();
  for (int it = 0; it < 24; ++it) {
    float s1 = 0.f, s2 = 0.f;
    if (inlds) {
      for (int i = t; i < ntot; i += 512) {
        float d = fmaxf(list[i] - tau, 0.f);
        s1 += d; s2 += d * d;
      }
    } else {
      for (int c = 0; c < NCH; ++c) {
        int n = cbase[c + 1] - cbase[c];
        for (int i = t; i < n; i += 512) {
          float d = fmaxf(gl[c * CHSZ + i] - tau, 0.f);
          s1 += d; s2 += d * d;
        }
      }
    }
    for (int o = 32; o > 0; o >>= 1) { s1 += __shfl_down(s1, o); s2 += __shfl_down(s2, o); }
    if (lane == 0) { rs1[w] = s1; rs2[w] = s2; }
    __syncthreads();
    if (t == 0) {
      float S1 = 0.f, S2 = 0.f;
#pragma unroll
      for (int q = 0; q < 8; ++q) { S1 += rs1[q]; S2 += rs2[q]; }
      float dt = (S2 - 1.f) / (2.f * fmaxf(S1, 1e-12f));
      tsh = tau + dt; dsh = dt;
    }
    __syncthreads();
    tau = tsh;
    if (fabsf(dsh) < 1e-7f) break;
  }
  if (t == 0) T[bh] = tau;
  if (t < 64) xout[bh * 64 + t] = 0.f;
}

// xi_new[b,h,d] += sum_i ((z-T)+)^2 * V[h,i,d]; skip all-zero groups of 8 rows
__global__ __launch_bounds__(512) void xiupd_k(const float* __restrict__ z, const float* __restrict__ T,
                                               const u16* __restrict__ Vbuf, float* __restrict__ xi_new) {
  int h = blockIdx.y;
  int row0 = blockIdx.x * 1024;
  int t = threadIdx.x;
  int b = t >> 6, d = t & 63;
  __shared__ float zs[8][1024];
#pragma unroll
  for (int j = 0; j < 16; ++j) {
    int f = t + j * 512;
    int bb = f >> 10, i = f & 1023;
    int row = row0 + i;
    zs[bb][i] = (row < GN) ? z[((size_t)(bb * 4 + h)) * GN + row] : -1e30f;
  }
  __syncthreads();
  float Tv = T[b * 4 + h];
  float acc = 0.f;
  for (int ii = 0; ii < 1024; ii += 8) {
    float wv[8];
#pragma unroll
    for (int e = 0; e < 8; ++e) wv[e] = zs[b][ii + e] - Tv;
    float m8 = wv[0];
#pragma unroll
    for (int e = 1; e < 8; ++e) m8 = fmaxf(m8, wv[e]);
    if (m8 <= 0.f) continue;
    const u16* vrow = Vbuf + ((size_t)h * GN + row0 + ii) * HD + d;
#pragma unroll
    for (int e = 0; e < 8; ++e) {
      float we = fmaxf(wv[e], 0.f);
      float v = bf2f(vrow[e * HD]);
      acc += we * we * v;
    }
  }
  atomicAdd(&xi_new[b * 256 + h * 64 + d], acc);
}

__global__ __launch_bounds__(256) void finout_k(const float* __restrict__ xi, const float* __restrict__ Wo,
                                                float* __restrict__ outs) {
  int w = threadIdx.x >> 6, lane = threadIdx.x & 63;
  int flat = blockIdx.x * 4 + w;
  int b = flat >> 11, o = flat & 2047;
  const float4* wp = (const float4*)(Wo + (size_t)o * 256);
  const float4* xp = (const float4*)(xi + b * 256);
  float4 w4 = wp[lane];
  float4 x4 = xp[lane];
  float acc = w4.x * x4.x + w4.y * x4.y + w4.z * x4.z + w4.w * x4.w;
  for (int o2 = 32; o2 > 0; o2 >>= 1) acc += __shfl_down(acc, o2);
  if (lane == 0) outs[flat] = acc;
}

__global__ __launch_bounds__(256) void bcast_k(const float* __restrict__ outs, float* __restrict__ out) {
  int idx = blockIdx.x * 256 + threadIdx.x;   // float4 index; rows are 512 float4
  int row = idx >> 9, o = idx & 511;
  int b = row >> 11;
  ((float4*)out)[idx] = ((const float4*)outs)[b * 512 + o];
}

// ---------------- launch ----------------
extern "C" void kernel_launch(void* const* d_in, const int* in_sizes, int n_in,
                              void* d_out, int out_size, void* d_ws, size_t ws_size,
                              hipStream_t stream) {
  const float* qe = (const float*)d_in[1];
  const float* mb = (const float*)d_in[2];
  const float* Wq = (const float*)d_in[3];
  const float* Wk = (const float*)d_in[4];
  const float* Wv = (const float*)d_in[5];
  const float* Wo = (const float*)d_in[6];
  const float* lb = (const float*)d_in[7];
  const float* gq = (const float*)d_in[8];
  const float* bq = (const float*)d_in[9];
  const float* gm = (const float*)d_in[10];
  const float* bm = (const float*)d_in[11];

  char* ob = (char*)d_out;
  u16*   ln    = (u16*)(ob + LN_OFF);
  float* z     = (float*)(ob + Z_OFF);
  float* glist = (float*)(ob + GLIST_OFF);
  float* phist = (float*)(ob + PHIST_OFF);
  u16*   Kb    = (u16*)(ob + K_OFF);
  u16*   Vb    = (u16*)(ob + V_OFF);
  u16*   wkv   = (u16*)(ob + WKV_OFF);
  float* bmax  = (float*)(ob + BMAX_OFF);
  int*   ccnt  = (int*)(ob + CCNT_OFF);

  char* ws = (char*)d_ws;
  float* xiA  = (float*)(ws + XIA_OFF);
  float* xiB  = (float*)(ws + XIB_OFF);
  float* T    = (float*)(ws + T_OFF);
  float* beta = (float*)(ws + BETA_OFF);
  float* outs = (float*)(ws + OUTS_OFF);
  float* ep   = (float*)(ws + EP_OFF);

  row_ln<<<12500, 256, 0, stream>>>(mb, gm, bm, ln);
  wconv<<<384, 256, 0, stream>>>(Wk, Wv, wkv);
  qprep<<<8, 256, 0, stream>>>(qe, Wq, gq, bq, lb, xiA, beta);
  gemm_kv<<<dim3(782, 2), 256, 0, stream>>>(ln, wkv, Kb, Vb);

  float* xin = xiA;
  float* xout = xiB;
  for (int s = 0; s < 3; ++s) {
    scores_k<<<dim3(782, 4), 256, 0, stream>>>(Kb, xin, beta, z, bmax);
    hist_k<<<dim3(NCH, 32), 256, 0, stream>>>(z, bmax, phist);
    etau_k<<<32, 256, 0, stream>>>(phist, bmax, ep);
    collect_k<<<dim3(NCH, 32), 256, 0, stream>>>(z, ep, glist, ccnt);
    esolve_k<<<32, 512, 0, stream>>>(glist, ccnt, ep, T, xout);
    xiupd_k<<<dim3(49, 4), 512, 0, stream>>>(z, T, Vb, xout);
    float* tmp = xin; xin = xout; xout = tmp;
  }

  finout_k<<<4096, 256, 0, stream>>>(xin, Wo, outs);
  bcast_k<<<32768, 256, 0, stream>>>(outs, (float*)d_out);
}